// Round 19
// baseline (75.846 us; speedup 1.0000x reference)
//
#include <hip/hip_runtime.h>

typedef __bf16 bf16_t;
typedef __bf16 bf16x4 __attribute__((ext_vector_type(4)));
typedef __bf16 bf16x8 __attribute__((ext_vector_type(8)));
typedef float  f32x4  __attribute__((ext_vector_type(4)));

#define B_SZ  16
#define L_SEQ 2048
#define D_H   64
#define QB    64
#define NT128 16                 // L_SEQ / 128
#define TILE_HW (128 * D_H)      // 8192 bf16 per 128-tile image (16 KB)
#define IMG_ELEMS ((size_t)B_SZ * NT128 * TILE_HW)   // per tensor

// softmax is over (S/8); fold log2(e)/8 into Q so MFMA output is in log2 units
#define QSCALE 0.18033688011112043f

// ---------------- preproc: bf16 + transpose(V), LINEAR images (no swizzle: no LDS) ----
// K image:  K[b][kt*128+r][ch*8+w]  -> ko[r*64 + ch*8 + w]          (row-major [128][64])
// V image:  V[b][kt*128+k(pos)][d]  -> vo[d*128 + pos]              (row-major [64][128], phi-permuted pos)
//           pos = pc*8+pw;  vkb = pos[4:3] | pos[2]<<2 | pos[6:5]<<3;  k = vkb*4 + pos[1:0]
__global__ __launch_bounds__(256)
void preproc_kernel(const float* __restrict__ Kg, const float* __restrict__ Vg,
                    bf16_t* __restrict__ Kimg, bf16_t* __restrict__ Vimg)
{
    const int kt = blockIdx.x, b = blockIdx.y, z = blockIdx.z;   // z = quarter
    const int t  = threadIdx.x;
    const size_t src = (size_t)b * L_SEQ * D_H + (size_t)kt * 128 * D_H;
    bf16_t* ko = Kimg + (size_t)(b * NT128 + kt) * TILE_HW;
    bf16_t* vo = Vimg + (size_t)(b * NT128 + kt) * TILE_HW;

    {
        const int u = z * 256 + t, r = u >> 3, ch = u & 7;
        const float* p = Kg + src + r * 64 + ch * 8;
        const f32x4 a = *reinterpret_cast<const f32x4*>(p);
        const f32x4 c = *reinterpret_cast<const f32x4*>(p + 4);
        bf16x8 kk;
#pragma unroll
        for (int j = 0; j < 4; ++j) { kk[j] = (bf16_t)a[j]; kk[4 + j] = (bf16_t)c[j]; }
        *reinterpret_cast<bf16x8*>(&ko[r * 64 + ch * 8]) = kk;
    }
    {
        const int d = t & 63, pc = (t >> 6) + z * 4;
        bf16x8 vv;
#pragma unroll
        for (int pw = 0; pw < 8; ++pw) {
            const int pos = pc * 8 + pw;
            const int vkb = ((pos >> 3) & 3) | (((pos >> 2) & 1) << 2) | (((pos >> 5) & 3) << 3);
            const int k   = (vkb << 2) | (pos & 3);
            vv[pw] = (bf16_t)Vg[src + (size_t)k * 64 + d];
        }
        *reinterpret_cast<bf16x8*>(&vo[d * 128 + pc * 8]) = vv;
    }
}

// ---------------- main kernel: NO LDS, NO barriers — MFMA operands straight from L2 ----
// r4 scaffold: 512 blocks x 4 waves, balanced qt pairing (co-resident blocks get
// qt=31-qi and qt=qi), each wave owns 16 q-rows, 128 keys per iteration.
__global__ __launch_bounds__(256, 2)
void attn_l2_kernel(const float* __restrict__ Qg, float* __restrict__ Og,
                    const bf16_t* __restrict__ Kimg, const bf16_t* __restrict__ Vimg)
{
    const int lin  = blockIdx.x;          // 0..511
    const int xcd  = lin & 7;
    const int slot = lin >> 3;            // 0..63
    const int half = slot >> 5;
    const int qi   = slot & 31;
    const int b    = xcd * 2 + half;      // 2 batches per XCD -> images L2-resident
    const int qt   = half ? qi : (31 - qi);

    const int tid  = threadIdx.x;
    const int lane = tid & 63;
    const int lg   = lane >> 4;
    const int lc   = lane & 15;

    const size_t bbase = (size_t)b * L_SEQ * D_H;
    const bf16_t* kimg = Kimg + (size_t)b * NT128 * TILE_HW;
    const bf16_t* vimg = Vimg + (size_t)b * NT128 * TILE_HW;

    // ---- Q fragment (B-operand of swapped QK: lane lc <-> q, (lg,j) <-> d) ----
    const int qrow = qt * QB + (tid >> 6) * 16 + lc;
    bf16x8 qa[2];
#pragma unroll
    for (int h = 0; h < 2; ++h) {
        const float* qp = Qg + bbase + (size_t)qrow * D_H + h * 32 + lg * 8;
        const f32x4 f0 = *reinterpret_cast<const f32x4*>(qp);
        const f32x4 f1 = *reinterpret_cast<const f32x4*>(qp + 4);
        bf16x8 a;
#pragma unroll
        for (int j = 0; j < 4; ++j) { a[j] = (bf16_t)(f0[j] * QSCALE); a[4 + j] = (bf16_t)(f1[j] * QSCALE); }
        qa[h] = a;
    }

    f32x4 o[4];
#pragma unroll
    for (int dt = 0; dt < 4; ++dt) o[dt] = (f32x4){0.f, 0.f, 0.f, 0.f};
    float m = -1e30f, l = 0.f;   // per-lane l partial in frame m

    const int nkt = (qt + 2) >> 1;        // number of 128-wide K tiles (last masked)

    // per-lane fragment offsets within a tile image (bf16 elements)
    const int koff = lc * 64 + lg * 8;    // + n*16*64 + h*32
    const int voff = lc * 128 + lg * 8;   // + dt*16*128 + ks*32

    for (int kt = 0; kt < nkt; ++kt) {
        const bool last = (kt == nkt - 1);
        const int kb0 = kt * 128;
        const bf16_t* kp = kimg + (size_t)kt * TILE_HW + koff;
        const bf16_t* vp = vimg + (size_t)kt * TILE_HW + voff;

        // ---- load all 16 K fragments (compiler batches; L2-resident) ----
        bf16x8 kf[16];
#pragma unroll
        for (int n = 0; n < 8; ++n)
#pragma unroll
            for (int h = 0; h < 2; ++h)
                kf[n * 2 + h] = *reinterpret_cast<const bf16x8*>(kp + n * (16 * 64) + h * 32);

        // ---- S^T = K Q^T (log2 units): sc[n][r] = S[k=kb0+n*16+lg*4+r][q=qrow] ----
        f32x4 sc[8];
        __builtin_amdgcn_s_setprio(1);
#pragma unroll
        for (int n = 0; n < 8; ++n) {
            f32x4 acc = (f32x4){0.f, 0.f, 0.f, 0.f};
            acc = __builtin_amdgcn_mfma_f32_16x16x32_bf16(kf[n * 2 + 0], qa[0], acc, 0, 0, 0);
            acc = __builtin_amdgcn_mfma_f32_16x16x32_bf16(kf[n * 2 + 1], qa[1], acc, 0, 0, 0);
            sc[n] = acc;
        }
        __builtin_amdgcn_s_setprio(0);

        if (last) {
#pragma unroll
            for (int n = 0; n < 8; ++n)
#pragma unroll
                for (int r = 0; r < 4; ++r)
                    if (kb0 + n * 16 + lg * 4 + r > qrow) sc[n][r] = -1e30f;
        }

        // ---- load all 16 V fragments (overlaps the softmax below) ----
        bf16x8 vf[16];
#pragma unroll
        for (int ks = 0; ks < 4; ++ks)
#pragma unroll
            for (int dt = 0; dt < 4; ++dt)
                vf[ks * 4 + dt] = *reinterpret_cast<const bf16x8*>(vp + dt * (16 * 128) + ks * 32);

        // ---- defer-max online softmax (per-lane; cross-lane only on slow path) ----
        float mxp = fmaxf(fmaxf(sc[0][0], sc[0][1]), fmaxf(sc[0][2], sc[0][3]));
#pragma unroll
        for (int n = 1; n < 8; ++n)
            mxp = fmaxf(mxp, fmaxf(fmaxf(sc[n][0], sc[n][1]), fmaxf(sc[n][2], sc[n][3])));
        if (!__all(mxp <= m + 8.0f)) {
            float mx = mxp;
            mx = fmaxf(mx, __shfl_xor(mx, 16));
            mx = fmaxf(mx, __shfl_xor(mx, 32));
            const float mn = fmaxf(m, mx);
            const float alpha = exp2f(m - mn);
            m = mn;
            l *= alpha;
#pragma unroll
            for (int dt = 0; dt < 4; ++dt)
#pragma unroll
                for (int r = 0; r < 4; ++r) o[dt][r] *= alpha;
        }
        // P packed directly into the PV B-operand layout (phi-permuted V^T image)
        bf16x8 w[4];
        float rs = 0.f;
#pragma unroll
        for (int n = 0; n < 8; ++n) {
            const float p0 = exp2f(sc[n][0] - m), p1 = exp2f(sc[n][1] - m);
            const float p2 = exp2f(sc[n][2] - m), p3 = exp2f(sc[n][3] - m);
            rs += (p0 + p1) + (p2 + p3);
            const int wi = n >> 1, off = (n & 1) * 4;
            w[wi][off + 0] = (bf16_t)p0; w[wi][off + 1] = (bf16_t)p1;
            w[wi][off + 2] = (bf16_t)p2; w[wi][off + 3] = (bf16_t)p3;
        }
        l += rs;

        // ---- O^T += V^T P : both operands in registers ----
        __builtin_amdgcn_s_setprio(1);
#pragma unroll
        for (int ks = 0; ks < 4; ++ks)
#pragma unroll
            for (int dt = 0; dt < 4; ++dt)
                o[dt] = __builtin_amdgcn_mfma_f32_16x16x32_bf16(vf[ks * 4 + dt], w[ks], o[dt], 0, 0, 0);
        __builtin_amdgcn_s_setprio(0);
    }

    // ---- epilogue: reduce per-lane l across the 4 lane-groups, then O = O^T / l ----
    float lr = l;
    lr += __shfl_xor(lr, 16);
    lr += __shfl_xor(lr, 32);
    const float inv = 1.0f / lr;
#pragma unroll
    for (int dt = 0; dt < 4; ++dt) {
        f32x4 val = { o[dt][0] * inv, o[dt][1] * inv, o[dt][2] * inv, o[dt][3] * inv };
        *reinterpret_cast<f32x4*>(Og + bbase + (size_t)qrow * D_H + dt * 16 + lg * 4) = val;
    }
}

// ---------------- fallback (no-ws path, round-6 kernel) ----------------
__global__ __launch_bounds__(256, 2)
void attn_fwd_fb(const float* __restrict__ Qg, const float* __restrict__ Kg,
                 const float* __restrict__ Vg, float* __restrict__ Og)
{
    const int lin  = blockIdx.x;
    const int xcd  = lin & 7;
    const int slot = lin >> 3;
    const int half = slot >> 5;
    const int qi   = slot & 31;
    const int b    = xcd * 2 + half;
    const int qt   = half ? qi : (31 - qi);

    const int tid  = threadIdx.x;
    const int lane = tid & 63;
    const int lg   = lane >> 4;
    const int lc   = lane & 15;
    const int lc7  = lc & 7;

    __shared__ __align__(16) bf16_t K_lds[2][128 * 64];
    __shared__ __align__(16) bf16_t Vt_lds[2][64 * 128];

    const size_t bbase = (size_t)b * L_SEQ * D_H;
    const int qrow = qt * 64 + (tid >> 6) * 16 + lc;
    bf16x8 qa[2];
#pragma unroll
    for (int h = 0; h < 2; ++h) {
        const float* qp = Qg + bbase + (size_t)qrow * D_H + h * 32 + lg * 8;
        const f32x4 f0 = *reinterpret_cast<const f32x4*>(qp);
        const f32x4 f1 = *reinterpret_cast<const f32x4*>(qp + 4);
        bf16x8 a;
#pragma unroll
        for (int j = 0; j < 4; ++j) { a[j] = (bf16_t)(f0[j] * QSCALE); a[4 + j] = (bf16_t)(f1[j] * QSCALE); }
        qa[h] = a;
    }
    f32x4 o[4];
#pragma unroll
    for (int dt = 0; dt < 4; ++dt) o[dt] = (f32x4){0.f, 0.f, 0.f, 0.f};
    float m = -1e30f, l = 0.f;
    const int nkt = (qt + 2) >> 1;
    const int vkb  = tid & 31;
    const int vdg  = tid >> 5;
    const int vpos = ((vkb >> 3) << 5) + ((vkb & 3) << 3) + (((vkb >> 2) & 1) << 2);
    f32x4 kreg[8], vreg[8];

    auto issueK = [&](int kt) {
        const int kbase = kt * 128;
#pragma unroll
        for (int i = 0; i < 4; ++i) {
            const int u = i * 256 + tid;
            const int r = u >> 3, ch = u & 7;
            const float* p = Kg + bbase + (size_t)(kbase + r) * D_H + ch * 8;
            kreg[2 * i]     = *reinterpret_cast<const f32x4*>(p);
            kreg[2 * i + 1] = *reinterpret_cast<const f32x4*>(p + 4);
        }
    };
    auto issueV = [&](int kt) {
        const int kbase = kt * 128;
#pragma unroll
        for (int d2 = 0; d2 < 2; ++d2)
#pragma unroll
            for (int i = 0; i < 4; ++i)
                vreg[d2 * 4 + i] = *reinterpret_cast<const f32x4*>(
                    Vg + bbase + (size_t)(kbase + vkb * 4 + i) * D_H + (vdg + d2 * 8) * 4);
    };
    auto writeK = [&](int buf) {
#pragma unroll
        for (int i = 0; i < 4; ++i) {
            const int u = i * 256 + tid;
            const int r = u >> 3, ch = u & 7;
            bf16x8 kk;
#pragma unroll
            for (int j = 0; j < 4; ++j) { kk[j] = (bf16_t)kreg[2 * i][j]; kk[4 + j] = (bf16_t)kreg[2 * i + 1][j]; }
            *reinterpret_cast<bf16x8*>(&K_lds[buf][r * 64 + ((ch ^ (r & 7)) << 3)]) = kk;
        }
    };
    auto writeV = [&](int buf) {
#pragma unroll
        for (int d2 = 0; d2 < 2; ++d2) {
            const int db = vdg + d2 * 8;
#pragma unroll
            for (int j = 0; j < 4; ++j) {
                const int d = db * 4 + j;
                bf16x4 cj = { (bf16_t)vreg[d2 * 4 + 0][j], (bf16_t)vreg[d2 * 4 + 1][j],
                              (bf16_t)vreg[d2 * 4 + 2][j], (bf16_t)vreg[d2 * 4 + 3][j] };
                const int hw = d * 128 + (((vpos >> 3) ^ (d & 7)) << 3) + (vpos & 7);
                *reinterpret_cast<bf16x4*>(&Vt_lds[buf][hw]) = cj;
            }
        }
    };

    issueK(0); issueV(0); writeK(0); writeV(0);
    __syncthreads();
    int cur = 0;
    for (int kt = 0; kt < nkt; ++kt) {
        const bool last = (kt == nkt - 1);
        const int kbase = kt * 128;
        if (!last) issueK(kt + 1);
        f32x4 sc[8];
#pragma unroll
        for (int n = 0; n < 8; ++n) {
            f32x4 acc = (f32x4){0.f, 0.f, 0.f, 0.f};
#pragma unroll
            for (int h = 0; h < 2; ++h) {
                const int hw = (n * 16 + lc) * 64 + ((((h << 2) | lg) ^ lc7) << 3);
                const bf16x8 kkb = *reinterpret_cast<const bf16x8*>(&K_lds[cur][hw]);
                acc = __builtin_amdgcn_mfma_f32_16x16x32_bf16(kkb, qa[h], acc, 0, 0, 0);
            }
            sc[n] = acc;
        }
        if (!last) issueV(kt + 1);
        if (last) {
#pragma unroll
            for (int n = 0; n < 8; ++n)
#pragma unroll
                for (int r = 0; r < 4; ++r)
                    if (kbase + n * 16 + lg * 4 + r > qrow) sc[n][r] = -1e30f;
        }
        float mxp = fmaxf(fmaxf(sc[0][0], sc[0][1]), fmaxf(sc[0][2], sc[0][3]));
#pragma unroll
        for (int n = 1; n < 8; ++n)
            mxp = fmaxf(mxp, fmaxf(fmaxf(sc[n][0], sc[n][1]), fmaxf(sc[n][2], sc[n][3])));
        if (!__all(mxp <= m + 8.0f)) {
            float mx = mxp;
            mx = fmaxf(mx, __shfl_xor(mx, 16));
            mx = fmaxf(mx, __shfl_xor(mx, 32));
            const float mn = fmaxf(m, mx);
            const float alpha = exp2f(m - mn);
            m = mn; l *= alpha;
#pragma unroll
            for (int dt = 0; dt < 4; ++dt)
#pragma unroll
                for (int r = 0; r < 4; ++r) o[dt][r] *= alpha;
        }
        bf16x8 w[4];
        float rs = 0.f;
#pragma unroll
        for (int n = 0; n < 8; ++n) {
            const float p0 = exp2f(sc[n][0] - m), p1 = exp2f(sc[n][1] - m);
            const float p2 = exp2f(sc[n][2] - m), p3 = exp2f(sc[n][3] - m);
            rs += (p0 + p1) + (p2 + p3);
            const int wi = n >> 1, off = (n & 1) * 4;
            w[wi][off + 0] = (bf16_t)p0; w[wi][off + 1] = (bf16_t)p1;
            w[wi][off + 2] = (bf16_t)p2; w[wi][off + 3] = (bf16_t)p3;
        }
        l += rs;
        if (!last) writeK(cur ^ 1);
#pragma unroll
        for (int ks = 0; ks < 4; ++ks) {
#pragma unroll
            for (int dt = 0; dt < 4; ++dt) {
                const int hw = (dt * 16 + lc) * 128 + ((((ks << 2) | lg) ^ lc7) << 3);
                const bf16x8 vb = *reinterpret_cast<const bf16x8*>(&Vt_lds[cur][hw]);
                o[dt] = __builtin_amdgcn_mfma_f32_16x16x32_bf16(vb, w[ks], o[dt], 0, 0, 0);
            }
        }
        if (!last) writeV(cur ^ 1);
        __syncthreads();
        cur ^= 1;
    }
    float lr = l;
    lr += __shfl_xor(lr, 16);
    lr += __shfl_xor(lr, 32);
    const float inv = 1.0f / lr;
#pragma unroll
    for (int dt = 0; dt < 4; ++dt) {
        f32x4 val = { o[dt][0] * inv, o[dt][1] * inv, o[dt][2] * inv, o[dt][3] * inv };
        *reinterpret_cast<f32x4*>(Og + bbase + (size_t)qrow * D_H + dt * 16 + lg * 4) = val;
    }
}

extern "C" void kernel_launch(void* const* d_in, const int* in_sizes, int n_in,
                              void* d_out, int out_size, void* d_ws, size_t ws_size,
                              hipStream_t stream)
{
    const float* Q = (const float*)d_in[0];
    const float* K = (const float*)d_in[1];
    const float* V = (const float*)d_in[2];
    float* O = (float*)d_out;

    const size_t need = 2 * IMG_ELEMS * sizeof(bf16_t);   // 8 MB
    if (ws_size >= need) {
        bf16_t* Kimg = (bf16_t*)d_ws;
        bf16_t* Vimg = Kimg + IMG_ELEMS;
        preproc_kernel<<<dim3(NT128, B_SZ, 4), dim3(256), 0, stream>>>(K, V, Kimg, Vimg);
        attn_l2_kernel<<<dim3(512), dim3(256), 0, stream>>>(Q, O, Kimg, Vimg);
    } else {
        attn_fwd_fb<<<dim3(512), dim3(256), 0, stream>>>(Q, K, V, O);
    }
}

// Round 20
// 33.782 us; speedup vs baseline: 2.2452x; 2.2452x over previous
//
#include <hip/hip_runtime.h>

typedef __bf16 bf16_t;
typedef __bf16 bf16x4 __attribute__((ext_vector_type(4)));
typedef __bf16 bf16x8 __attribute__((ext_vector_type(8)));
typedef float  f32x4  __attribute__((ext_vector_type(4)));

#define B_SZ  16
#define L_SEQ 2048
#define D_H   64
#define QB    64
#define KB    128
#define NQT   (L_SEQ / QB)   // 32

// softmax is over (S/8); fold log2(e)/8 into Q so MFMA output is in log2 units
#define QSCALE 0.18033688011112043f

// ---------------- producer/consumer kernel ----------------
// r4 scaffold: 512 blocks (balanced qt pairing, 2 batches/XCD), now 8 waves each.
// waves 0-3 (consumers): r4 compute engine, 16 q-rows per wave, NO global K/V access.
// waves 4-7 (producers): r4 staging engine on 256 threads, NO FLOPs.
// Double-buffered LDS; 1 barrier/iter; producer stages tile j+1 while consumers compute j.
__global__ __launch_bounds__(512, 4)
void attn_pc_kernel(const float* __restrict__ Qg, const float* __restrict__ Kg,
                    const float* __restrict__ Vg, float* __restrict__ Og)
{
    const int lin  = blockIdx.x;          // 0..511
    const int xcd  = lin & 7;
    const int slot = lin >> 3;            // 0..63
    const int half = slot >> 5;
    const int qi   = slot & 31;
    const int b    = xcd * 2 + half;      // 2 batches per XCD -> K/V L2-resident
    const int qt   = half ? qi : (31 - qi);

    const int tid  = threadIdx.x;
    const int wave = tid >> 6;            // 0..7
    const int lane = tid & 63;
    const int lg   = lane >> 4;
    const int lc   = lane & 15;

    __shared__ __align__(16) bf16_t K_lds[2][KB][72];      // r4 padded layout, 36 KB
    __shared__ __align__(16) bf16_t Vt_lds[2][D_H][136];   // transposed+phi, 34 KB

    const size_t bbase = (size_t)b * L_SEQ * D_H;
    const int nkt = (qt + 2) >> 1;        // number of 128-wide K tiles (last masked)

    if (wave >= 4) {
        // ================= PRODUCER (waves 4-7, 256 threads) =================
        const int pt   = tid - 256;       // 0..255
        const int vkb  = pt & 31;         // k-block (4 rows) 0..31
        const int vdg  = pt >> 5;         // 0..7 -> d-blocks vdg, vdg+8
        const int vpos = ((vkb >> 3) << 5) + ((vkb & 3) << 3) + (((vkb >> 2) & 1) << 2);

        f32x4 kreg[8], vreg[8];

        auto issueK = [&](int kt) {
            const int kbase = kt * KB;
#pragma unroll
            for (int i = 0; i < 8; ++i) {
                const int f = i * 256 + pt;
                const int r = f >> 4, c4 = (f & 15) * 4;
                kreg[i] = *reinterpret_cast<const f32x4*>(Kg + bbase + (size_t)(kbase + r) * D_H + c4);
            }
        };
        auto issueV = [&](int kt) {
            const int kbase = kt * KB;
#pragma unroll
            for (int d2 = 0; d2 < 2; ++d2)
#pragma unroll
                for (int i = 0; i < 4; ++i)
                    vreg[d2 * 4 + i] = *reinterpret_cast<const f32x4*>(
                        Vg + bbase + (size_t)(kbase + vkb * 4 + i) * D_H + (vdg + d2 * 8) * 4);
        };
        auto writeK = [&](int buf) {
#pragma unroll
            for (int i = 0; i < 8; ++i) {
                const int f = i * 256 + pt;
                const int r = f >> 4, c4 = (f & 15) * 4;
                bf16x4 k4 = { (bf16_t)kreg[i][0], (bf16_t)kreg[i][1], (bf16_t)kreg[i][2], (bf16_t)kreg[i][3] };
                *reinterpret_cast<bf16x4*>(&K_lds[buf][r][c4]) = k4;
            }
        };
        auto writeV = [&](int buf) {
#pragma unroll
            for (int d2 = 0; d2 < 2; ++d2) {
                const int db = vdg + d2 * 8;
#pragma unroll
                for (int j = 0; j < 4; ++j) {
                    bf16x4 cj = { (bf16_t)vreg[d2 * 4 + 0][j], (bf16_t)vreg[d2 * 4 + 1][j],
                                  (bf16_t)vreg[d2 * 4 + 2][j], (bf16_t)vreg[d2 * 4 + 3][j] };
                    *reinterpret_cast<bf16x4*>(&Vt_lds[buf][db * 4 + j][vpos]) = cj;
                }
            }
        };

        issueK(0); issueV(0); writeK(0); writeV(0);
        __syncthreads();                                   // prologue barrier
        for (int kt = 0; kt < nkt; ++kt) {
            if (kt + 1 < nkt) {
                issueK(kt + 1); issueV(kt + 1);
                writeK((kt + 1) & 1); writeV((kt + 1) & 1);
            }
            __syncthreads();                               // tile kt+1 ready / kt consumed
        }
    } else {
        // ================= CONSUMER (waves 0-3) =================
        const int qrow = qt * QB + wave * 16 + lc;
        bf16x8 qa[2];
#pragma unroll
        for (int h = 0; h < 2; ++h) {
            const float* qp = Qg + bbase + (size_t)qrow * D_H + h * 32 + lg * 8;
            const f32x4 f0 = *reinterpret_cast<const f32x4*>(qp);
            const f32x4 f1 = *reinterpret_cast<const f32x4*>(qp + 4);
            bf16x8 a;
#pragma unroll
            for (int j = 0; j < 4; ++j) { a[j] = (bf16_t)(f0[j] * QSCALE); a[4 + j] = (bf16_t)(f1[j] * QSCALE); }
            qa[h] = a;
        }

        f32x4 o[4];
#pragma unroll
        for (int dt = 0; dt < 4; ++dt) o[dt] = (f32x4){0.f, 0.f, 0.f, 0.f};
        float m = -1e30f, l = 0.f;        // per-lane l partial in frame m

        __syncthreads();                                   // prologue barrier
        for (int kt = 0; kt < nkt; ++kt) {
            const bool last = (kt == nkt - 1);
            const int kbase = kt * KB;
            const int cur   = kt & 1;

            // ---- S^T = K Q^T (log2 units): sc[n][r] = S[k=kbase+n*16+lg*4+r][q=qrow] ----
            f32x4 sc[8];
            __builtin_amdgcn_s_setprio(1);
#pragma unroll
            for (int n = 0; n < 8; ++n) {
                f32x4 acc = (f32x4){0.f, 0.f, 0.f, 0.f};
#pragma unroll
                for (int h = 0; h < 2; ++h) {
                    const bf16x8 kb = *reinterpret_cast<const bf16x8*>(&K_lds[cur][n * 16 + lc][h * 32 + lg * 8]);
                    acc = __builtin_amdgcn_mfma_f32_16x16x32_bf16(kb, qa[h], acc, 0, 0, 0);
                }
                sc[n] = acc;
            }
            __builtin_amdgcn_s_setprio(0);
            if (last) {
#pragma unroll
                for (int n = 0; n < 8; ++n)
#pragma unroll
                    for (int r = 0; r < 4; ++r)
                        if (kbase + n * 16 + lg * 4 + r > qrow) sc[n][r] = -1e30f;
            }

            // ---- defer-max online softmax (per-lane; cross-lane only on slow path) ----
            float mxp = fmaxf(fmaxf(sc[0][0], sc[0][1]), fmaxf(sc[0][2], sc[0][3]));
#pragma unroll
            for (int n = 1; n < 8; ++n)
                mxp = fmaxf(mxp, fmaxf(fmaxf(sc[n][0], sc[n][1]), fmaxf(sc[n][2], sc[n][3])));
            if (!__all(mxp <= m + 8.0f)) {
                float mx = mxp;
                mx = fmaxf(mx, __shfl_xor(mx, 16));
                mx = fmaxf(mx, __shfl_xor(mx, 32));
                const float mn = fmaxf(m, mx);
                const float alpha = exp2f(m - mn);
                m = mn;
                l *= alpha;
#pragma unroll
                for (int dt = 0; dt < 4; ++dt)
#pragma unroll
                    for (int r = 0; r < 4; ++r) o[dt][r] *= alpha;
            }
            // P packed directly into the PV B-operand layout (phi-permuted V^T)
            bf16x8 w[4];
            float rs = 0.f;
#pragma unroll
            for (int n = 0; n < 8; ++n) {
                const float p0 = exp2f(sc[n][0] - m), p1 = exp2f(sc[n][1] - m);
                const float p2 = exp2f(sc[n][2] - m), p3 = exp2f(sc[n][3] - m);
                rs += (p0 + p1) + (p2 + p3);
                const int wi = n >> 1, off = (n & 1) * 4;
                w[wi][off + 0] = (bf16_t)p0; w[wi][off + 1] = (bf16_t)p1;
                w[wi][off + 2] = (bf16_t)p2; w[wi][off + 3] = (bf16_t)p3;
            }
            l += rs;

            // ---- O^T += V^T P : P straight from registers ----
            __builtin_amdgcn_s_setprio(1);
#pragma unroll
            for (int ks = 0; ks < 4; ++ks) {
#pragma unroll
                for (int dt = 0; dt < 4; ++dt) {
                    const bf16x8 vb = *reinterpret_cast<const bf16x8*>(&Vt_lds[cur][dt * 16 + lc][ks * 32 + lg * 8]);
                    o[dt] = __builtin_amdgcn_mfma_f32_16x16x32_bf16(vb, w[ks], o[dt], 0, 0, 0);
                }
            }
            __builtin_amdgcn_s_setprio(0);

            __syncthreads();                               // tile kt consumed / kt+1 ready
        }

        // ---- epilogue: reduce per-lane l, then O = O^T / l ----
        float lr = l;
        lr += __shfl_xor(lr, 16);
        lr += __shfl_xor(lr, 32);
        const float inv = 1.0f / lr;
#pragma unroll
        for (int dt = 0; dt < 4; ++dt) {
            f32x4 val = { o[dt][0] * inv, o[dt][1] * inv, o[dt][2] * inv, o[dt][3] * inv };
            *reinterpret_cast<f32x4*>(Og + bbase + (size_t)qrow * D_H + dt * 16 + lg * 4) = val;
        }
    }
}

extern "C" void kernel_launch(void* const* d_in, const int* in_sizes, int n_in,
                              void* d_out, int out_size, void* d_ws, size_t ws_size,
                              hipStream_t stream)
{
    const float* Q = (const float*)d_in[0];
    const float* K = (const float*)d_in[1];
    const float* V = (const float*)d_in[2];
    float* O = (float*)d_out;
    attn_pc_kernel<<<dim3(NQT * B_SZ), dim3(512), 0, stream>>>(Q, K, V, O);
}